// Round 1
// baseline (247.554 us; speedup 1.0000x reference)
//
#include <hip/hip_runtime.h>

// Problem constants (B=8192, S=32, N=128, K=64, M=3)
#define BATCH 8192
#define NBLK  2048            // 4 batches per block, one per wave
#define EPSF  1e-9f
#define C_LD  36              // per-tile |C| LDS leading dim (32 cols + pad)
#define C_SZ  (32 * C_LD)     // 1152 floats per wave (4608 B)

typedef float floatx16 __attribute__((ext_vector_type(16)));
typedef short shortx8  __attribute__((ext_vector_type(8)));

// insert v into descending top-4
__device__ __forceinline__ void ins4(float v, float& t0, float& t1, float& t2, float& t3) {
    float m;
    m = fminf(t0, v); t0 = fmaxf(t0, v); v = m;
    m = fminf(t1, v); t1 = fmaxf(t1, v); v = m;
    m = fminf(t2, v); t2 = fmaxf(t2, v); v = m;
    t3 = fmaxf(t3, v);
}

// merge a second descending top-4 (b0..b3) into t0..t3 (bitonic)
__device__ __forceinline__ void merge4(float& t0, float& t1, float& t2, float& t3,
                                       float b0, float b1, float b2, float b3) {
    float c0 = fmaxf(t0, b3);
    float c1 = fmaxf(t1, b2);
    float c2 = fmaxf(t2, b1);
    float c3 = fmaxf(t3, b0);
    float d0 = fmaxf(c0, c2), d2 = fminf(c0, c2);
    float d1 = fmaxf(c1, c3), d3 = fminf(c1, c3);
    t0 = fmaxf(d0, d1); t1 = fminf(d0, d1);
    t2 = fmaxf(d2, d3); t3 = fminf(d2, d3);
}

// One WAVE per batch. C = x(32x64) @ P(64x64) via split-bf16 MFMA:
//   x = hi + lo (bf16 truncation split, residual exact in fp32);
//   C = hi*hi + hi*lo + lo*hi accumulated fp32 (rel err ~1e-5).
// Fragments (32x32x16_bf16): A[m=lane&31][k=(lane>>5)*8+j],
//   B[k=(lane>>5)*8+j][n=lane&31], C/D col=lane&31,
//   row=(reg&3)+8*(reg>>2)+4*(lane>>5).
// Occupancy-focused revision: the per-wave |C| LDS tile is 32x36 and is
// REUSED for both 32-col tiles (top-4 folded per tile: lane handles row m,
// within-tile cols kg*16..+15, so the lane / lane^32 coverage is unchanged).
// LDS/block 34816 -> 18432 B. B-fragments are converted per-ks so bhi/blo
// liveness is 8 VGPRs, and __launch_bounds__(256,4) caps at 128 VGPR ->
// 4 waves/SIMD minimum.
__global__ __launch_bounds__(256, 4) void avl_main(
    const float* __restrict__ y_pred,
    const float* __restrict__ y_true,
    const float* __restrict__ P,   // [B][64][64]
    const float* __restrict__ X,   // [B][32][64]
    float* __restrict__ partial)   // [NBLK][2]: {violation_sum, logmse_sum}
{
    __shared__ float csh[4 * C_SZ];   // 18432 B
    __shared__ float red[8];

    const int tid  = threadIdx.x;
    const int wave = tid >> 6;
    const int lane = tid & 63;
    const int kg   = lane >> 5;   // K-half: this lane covers k = kg*8 + 16*ks + j
    const int m    = lane & 31;   // A row index == B col index == C col index
    const int b    = blockIdx.x * 4 + wave;

    float* Cw = csh + wave * C_SZ;

    // ---- load x in A-fragment order (8 dwordx4; rows cached across insts) ----
    const float* xg = X + (size_t)b * 2048 + m * 64 + kg * 8;
    float4 xa[4], xb[4];
#pragma unroll
    for (int ks = 0; ks < 4; ++ks) {
        xa[ks] = *(const float4*)(xg + ks * 16);
        xb[ks] = *(const float4*)(xg + ks * 16 + 4);
    }

    // ---- convert to hi/lo bf16 A-frags; fold |x| into the local top-4 ----
    float t0 = -1.f, t1 = -1.f, t2 = -1.f, t3 = -1.f;
    shortx8 ahi[4], alo[4];
#pragma unroll
    for (int ks = 0; ks < 4; ++ks) {
        const float v[8] = { xa[ks].x, xa[ks].y, xa[ks].z, xa[ks].w,
                             xb[ks].x, xb[ks].y, xb[ks].z, xb[ks].w };
#pragma unroll
        for (int i = 0; i < 8; ++i) {
            const float x = v[i];
            const unsigned bits = __float_as_uint(x);
            ahi[ks][i] = (short)(bits >> 16);
            const float hif = __uint_as_float(bits & 0xFFFF0000u);
            const float lof = x - hif;
            alo[ks][i] = (short)(__float_as_uint(lof) >> 16);
            ins4(fabsf(x), t0, t1, t2, t3);
        }
    }

    // ---- two 32-col tiles of C, sharing one per-wave LDS |C| tile ----
    const float* pg = P + (size_t)b * 4096 + (kg * 8) * 64 + m;
#pragma unroll
    for (int tile = 0; tile < 2; ++tile) {
        const float* pt = pg + tile * 32;

        // issue the whole tile's P loads up front (latency batching)
        float pv[32];
#pragma unroll
        for (int ks = 0; ks < 4; ++ks)
#pragma unroll
            for (int i = 0; i < 8; ++i)
                pv[ks * 8 + i] = pt[(ks * 16 + i) * 64];

        floatx16 acc;
#pragma unroll
        for (int r = 0; r < 16; ++r) acc[r] = 0.f;

        // convert per-ks (bhi/blo live range = 8 VGPRs), then 3 MFMAs
#pragma unroll
        for (int ks = 0; ks < 4; ++ks) {
            shortx8 bhi, blo;
#pragma unroll
            for (int i = 0; i < 8; ++i) {
                const float p = pv[ks * 8 + i];
                const unsigned bits = __float_as_uint(p);
                bhi[i] = (short)(bits >> 16);
                const float hif = __uint_as_float(bits & 0xFFFF0000u);
                const float lof = p - hif;
                blo[i] = (short)(__float_as_uint(lof) >> 16);
            }
            acc = __builtin_amdgcn_mfma_f32_32x32x16_bf16(alo[ks], bhi, acc, 0, 0, 0);
            acc = __builtin_amdgcn_mfma_f32_32x32x16_bf16(ahi[ks], blo, acc, 0, 0, 0);
            acc = __builtin_amdgcn_mfma_f32_32x32x16_bf16(ahi[ks], bhi, acc, 0, 0, 0);
        }

        // |C| -> LDS row-major (lanes hit distinct banks; 2-way between
        // half-waves is free). Same-wave write->read ordering is enforced
        // by compiler lgkmcnt waits (aliasing via Cw), as in the verified
        // predecessor.
#pragma unroll
        for (int reg = 0; reg < 16; ++reg) {
            const int row = (reg & 3) + 8 * (reg >> 2) + 4 * kg;
            Cw[row * C_LD + m] = fabsf(acc[reg]);
        }

        // fold this tile: lane handles row m, within-tile cols kg*16..+15
        const float* cr = Cw + m * C_LD + kg * 16;
#pragma unroll
        for (int t = 0; t < 4; ++t) {
            const float4 c = *(const float4*)(cr + 4 * t);
            ins4(c.x, t0, t1, t2, t3);
            ins4(c.y, t0, t1, t2, t3);
            ins4(c.z, t0, t1, t2, t3);
            ins4(c.w, t0, t1, t2, t3);
        }
        // next tile's LDS writes WAR-ordered against these reads by the
        // compiler (same buffer, same wave).
    }

    // merge complementary half (lane L and L+32 cover disjoint 64-value sets)
    {
        const float b0 = __shfl_xor(t0, 32, 64);
        const float b1 = __shfl_xor(t1, 32, 64);
        const float b2 = __shfl_xor(t2, 32, 64);
        const float b3 = __shfl_xor(t3, 32, 64);
        merge4(t0, t1, t2, t3, b0, b1, b2, b3);
    }

    float h = t0 / (t3 + EPSF);
#pragma unroll
    for (int msk = 1; msk <= 16; msk <<= 1)
        h = fmaxf(h, __shfl_xor(h, msk, 64));

    if (lane == 0) {
        const float yp = y_pred[b];
        red[wave] = fmaxf(h - yp, 0.f);
        const float lp = log2f(fmaxf(yp, EPSF));
        const float lt = log2f(fmaxf(y_true[b], EPSF));
        const float d = lt - lp;
        red[4 + wave] = d * d;
    }
    __syncthreads();
    if (tid == 0) {
        partial[blockIdx.x * 2 + 0] = red[0] + red[1] + red[2] + red[3];
        partial[blockIdx.x * 2 + 1] = red[4] + red[5] + red[6] + red[7];
    }
}

__global__ __launch_bounds__(256) void avl_final(
    const float* __restrict__ partial, float* __restrict__ out)
{
    const int tid  = threadIdx.x;
    const int wave = tid >> 6;
    const int lane = tid & 63;
    float s0 = 0.f, s1 = 0.f;
    for (int i = tid; i < NBLK; i += 256) {
        s0 += partial[2 * i + 0];
        s1 += partial[2 * i + 1];
    }
#pragma unroll
    for (int msk = 1; msk <= 32; msk <<= 1) {
        s0 += __shfl_xor(s0, msk, 64);
        s1 += __shfl_xor(s1, msk, 64);
    }
    __shared__ float r0[4], r1[4];
    if (lane == 0) { r0[wave] = s0; r1[wave] = s1; }
    __syncthreads();
    if (tid == 0) {
        const float vi = (r0[0] + r0[1] + r0[2] + r0[3]) * (1.0f / (float)BATCH);
        const float lm = (r1[0] + r1[1] + r1[2] + r1[3]) * (1.0f / (float)BATCH);
        out[0] = lm + 0.5f * vi;   // total_loss
        out[1] = lm;               // loss_logmse
        out[2] = vi;               // loss_violation
    }
}

extern "C" void kernel_launch(void* const* d_in, const int* in_sizes, int n_in,
                              void* d_out, int out_size, void* d_ws, size_t ws_size,
                              hipStream_t stream)
{
    const float* y_pred = (const float*)d_in[0];
    const float* y_true = (const float*)d_in[1];
    const float* P      = (const float*)d_in[2];
    const float* X      = (const float*)d_in[3];

    float* partial = (float*)d_ws;   // NBLK*2 floats = 16 KB
    avl_main<<<NBLK, 256, 0, stream>>>(y_pred, y_true, P, X, partial);
    avl_final<<<1, 256, 0, stream>>>(partial, (float*)d_out);
}

// Round 2
// 247.335 us; speedup vs baseline: 1.0009x; 1.0009x over previous
//
#include <hip/hip_runtime.h>

// Problem constants (B=8192, S=32, N=128, K=64, M=3)
#define BATCH 8192
#define NBLK  2048            // 4 batches per block, one per wave
#define EPSF  1e-9f
#define C_LD  36              // |C| LDS tile leading dim (measured 0 conflicts)
#define WLDS  2048            // floats per wave: union{ P dbuf 2x1024, C 32x36=1152 }

typedef float floatx16 __attribute__((ext_vector_type(16)));
typedef short shortx8  __attribute__((ext_vector_type(8)));
typedef __attribute__((address_space(1))) const void g_void;
typedef __attribute__((address_space(3))) void lds_void;

// insert v into descending top-4
__device__ __forceinline__ void ins4(float v, float& t0, float& t1, float& t2, float& t3) {
    float m;
    m = fminf(t0, v); t0 = fmaxf(t0, v); v = m;
    m = fminf(t1, v); t1 = fmaxf(t1, v); v = m;
    m = fminf(t2, v); t2 = fmaxf(t2, v); v = m;
    t3 = fmaxf(t3, v);
}

// merge a second descending top-4 (b0..b3) into t0..t3 (bitonic)
__device__ __forceinline__ void merge4(float& t0, float& t1, float& t2, float& t3,
                                       float b0, float b1, float b2, float b3) {
    float c0 = fmaxf(t0, b3);
    float c1 = fmaxf(t1, b2);
    float c2 = fmaxf(t2, b1);
    float c3 = fmaxf(t3, b0);
    float d0 = fmaxf(c0, c2), d2 = fminf(c0, c2);
    float d1 = fmaxf(c1, c3), d3 = fminf(c1, c3);
    t0 = fmaxf(d0, d1); t1 = fminf(d0, d1);
    t2 = fmaxf(d2, d3); t3 = fminf(d2, d3);
}

// One WAVE per batch. C = x(32x64) @ P(64x64) via split-bf16 MFMA (hi/lo
// truncation split, fp32 accumulate, rel err ~1e-5).
// R2 change (DRAM-efficiency): P is staged into LDS via contiguous
// global_load_lds DMA. Each k-chunk (16 rows = 4KB) is CONTIGUOUS in memory,
// loaded as 4 x 1KB burst instructions, double-buffered with counted
// vmcnt(4) waits so the next chunk stays in flight under the MFMAs.
// This replaces 64 scalar dword loads (2x128B scattered segments each) that
// thrashed DRAM at ~1.3 TB/s HBM.
// B-frag reads from linear [16][64] LDS: lane bank = m -> conflict-free.
// The |C| tile (32x36) is UNIONED into the P double-buffer (only used after
// all P reads; fenced with lgkmcnt(0)). LDS/wave = 8KB -> 32.8KB/block
// -> 4 blocks/CU resident.
__global__ __launch_bounds__(256, 4) void avl_main(
    const float* __restrict__ y_pred,
    const float* __restrict__ y_true,
    const float* __restrict__ P,   // [B][64][64]
    const float* __restrict__ X,   // [B][32][64]
    float* __restrict__ partial)   // [NBLK][2]: {violation_sum, logmse_sum}
{
    __shared__ float lds[4 * WLDS];   // 32768 B
    __shared__ float red[8];

    const int tid  = threadIdx.x;
    const int wave = tid >> 6;
    const int lane = tid & 63;
    const int kg   = lane >> 5;   // K-half: this lane covers k = kg*8 + 16*ks + j
    const int m    = lane & 31;   // A row index == B col index == C col index
    const int b    = blockIdx.x * 4 + wave;

    float* ldsw = lds + wave * WLDS;
    const float* Pg = P + (size_t)b * 4096;

    // DMA one 16-row (4KB contiguous) P chunk into buffer `buf`
#define STAGE(buf, kss) do {                                                       \
        const float* _s = Pg + (kss) * 1024 + lane * 4;                            \
        float* _d = ldsw + (buf) * 1024;                                           \
        __builtin_amdgcn_global_load_lds((g_void*)(_s),       (lds_void*)(_d),       16, 0, 0); \
        __builtin_amdgcn_global_load_lds((g_void*)(_s + 256), (lds_void*)(_d + 256), 16, 0, 0); \
        __builtin_amdgcn_global_load_lds((g_void*)(_s + 512), (lds_void*)(_d + 512), 16, 0, 0); \
        __builtin_amdgcn_global_load_lds((g_void*)(_s + 768), (lds_void*)(_d + 768), 16, 0, 0); \
    } while (0)

    // ---- issue x loads (8 dwordx4, A-fragment order) ----
    const float* xg = X + (size_t)b * 2048 + m * 64 + kg * 8;
    float4 xa[4], xb[4];
#pragma unroll
    for (int ks = 0; ks < 4; ++ks) {
        xa[ks] = *(const float4*)(xg + ks * 16);
        xb[ks] = *(const float4*)(xg + ks * 16 + 4);
    }

    // ---- issue first P chunk DMA (overlaps x conversion) ----
    STAGE(0, 0);

    // ---- convert x to hi/lo bf16 A-frags; fold |x| into local top-4 ----
    float t0 = -1.f, t1 = -1.f, t2 = -1.f, t3 = -1.f;
    shortx8 ahi[4], alo[4];
#pragma unroll
    for (int ks = 0; ks < 4; ++ks) {
        const float v[8] = { xa[ks].x, xa[ks].y, xa[ks].z, xa[ks].w,
                             xb[ks].x, xb[ks].y, xb[ks].z, xb[ks].w };
#pragma unroll
        for (int i = 0; i < 8; ++i) {
            const float x = v[i];
            const unsigned bits = __float_as_uint(x);
            ahi[ks][i] = (short)(bits >> 16);
            const float hif = __uint_as_float(bits & 0xFFFF0000u);
            const float lof = x - hif;
            alo[ks][i] = (short)(__float_as_uint(lof) >> 16);
            ins4(fabsf(x), t0, t1, t2, t3);
        }
    }

    // ---- K loop: 4 chunks, double-buffered DMA, both 32-col tiles per chunk ----
    floatx16 acc[2];
#pragma unroll
    for (int t = 0; t < 2; ++t)
#pragma unroll
        for (int r = 0; r < 16; ++r) acc[t][r] = 0.f;

#pragma unroll
    for (int ks = 0; ks < 4; ++ks) {
        if (ks < 3) {
            STAGE((ks + 1) & 1, ks + 1);
            asm volatile("s_waitcnt vmcnt(4)" ::: "memory");   // chunk ks landed, ks+1 in flight
        } else {
            asm volatile("s_waitcnt vmcnt(0)" ::: "memory");   // last chunk landed
        }
        __builtin_amdgcn_sched_barrier(0);

        const float* pb = ldsw + (ks & 1) * 1024;
        shortx8 bhi0, blo0, bhi1, blo1;
#pragma unroll
        for (int j = 0; j < 8; ++j) {
            const int row = (kg * 8 + j) * 64 + m;
            const float p0 = pb[row];        // tile 0 (cols 0..31)
            const float p1 = pb[row + 32];   // tile 1 (cols 32..63)
            const unsigned b0 = __float_as_uint(p0);
            bhi0[j] = (short)(b0 >> 16);
            const float h0 = __uint_as_float(b0 & 0xFFFF0000u);
            blo0[j] = (short)(__float_as_uint(p0 - h0) >> 16);
            const unsigned b1 = __float_as_uint(p1);
            bhi1[j] = (short)(b1 >> 16);
            const float h1 = __uint_as_float(b1 & 0xFFFF0000u);
            blo1[j] = (short)(__float_as_uint(p1 - h1) >> 16);
        }
        acc[0] = __builtin_amdgcn_mfma_f32_32x32x16_bf16(alo[ks], bhi0, acc[0], 0, 0, 0);
        acc[0] = __builtin_amdgcn_mfma_f32_32x32x16_bf16(ahi[ks], blo0, acc[0], 0, 0, 0);
        acc[0] = __builtin_amdgcn_mfma_f32_32x32x16_bf16(ahi[ks], bhi0, acc[0], 0, 0, 0);
        acc[1] = __builtin_amdgcn_mfma_f32_32x32x16_bf16(alo[ks], bhi1, acc[1], 0, 0, 0);
        acc[1] = __builtin_amdgcn_mfma_f32_32x32x16_bf16(ahi[ks], blo1, acc[1], 0, 0, 0);
        acc[1] = __builtin_amdgcn_mfma_f32_32x32x16_bf16(ahi[ks], bhi1, acc[1], 0, 0, 0);
    }

    // all P ds_reads must complete before the union space is overwritten by |C|
    asm volatile("s_waitcnt lgkmcnt(0)" ::: "memory");
    __builtin_amdgcn_sched_barrier(0);

    // ---- per-tile: |C| -> LDS (union with P buffers), row-major top-4 fold ----
    float* Cw = ldsw;
#pragma unroll
    for (int tile = 0; tile < 2; ++tile) {
#pragma unroll
        for (int reg = 0; reg < 16; ++reg) {
            const int row = (reg & 3) + 8 * (reg >> 2) + 4 * kg;
            Cw[row * C_LD + m] = fabsf(acc[tile][reg]);
        }
        // lane handles row m, within-tile cols kg*16..+15 (lane^32 covers rest)
        const float* cr = Cw + m * C_LD + kg * 16;
#pragma unroll
        for (int t = 0; t < 4; ++t) {
            const float4 c = *(const float4*)(cr + 4 * t);
            ins4(c.x, t0, t1, t2, t3);
            ins4(c.y, t0, t1, t2, t3);
            ins4(c.z, t0, t1, t2, t3);
            ins4(c.w, t0, t1, t2, t3);
        }
        // next tile's writes WAR-ordered against these reads by the compiler
    }

    // merge complementary half (lane L and L+32 cover disjoint 64-value sets)
    {
        const float b0 = __shfl_xor(t0, 32, 64);
        const float b1 = __shfl_xor(t1, 32, 64);
        const float b2 = __shfl_xor(t2, 32, 64);
        const float b3 = __shfl_xor(t3, 32, 64);
        merge4(t0, t1, t2, t3, b0, b1, b2, b3);
    }

    float h = t0 / (t3 + EPSF);
#pragma unroll
    for (int msk = 1; msk <= 16; msk <<= 1)
        h = fmaxf(h, __shfl_xor(h, msk, 64));

    if (lane == 0) {
        const float yp = y_pred[b];
        red[wave] = fmaxf(h - yp, 0.f);
        const float lp = log2f(fmaxf(yp, EPSF));
        const float lt = log2f(fmaxf(y_true[b], EPSF));
        const float d = lt - lp;
        red[4 + wave] = d * d;
    }
    __syncthreads();
    if (tid == 0) {
        partial[blockIdx.x * 2 + 0] = red[0] + red[1] + red[2] + red[3];
        partial[blockIdx.x * 2 + 1] = red[4] + red[5] + red[6] + red[7];
    }
#undef STAGE
}

__global__ __launch_bounds__(256) void avl_final(
    const float* __restrict__ partial, float* __restrict__ out)
{
    const int tid  = threadIdx.x;
    const int wave = tid >> 6;
    const int lane = tid & 63;
    float s0 = 0.f, s1 = 0.f;
    for (int i = tid; i < NBLK; i += 256) {
        s0 += partial[2 * i + 0];
        s1 += partial[2 * i + 1];
    }
#pragma unroll
    for (int msk = 1; msk <= 32; msk <<= 1) {
        s0 += __shfl_xor(s0, msk, 64);
        s1 += __shfl_xor(s1, msk, 64);
    }
    __shared__ float r0[4], r1[4];
    if (lane == 0) { r0[wave] = s0; r1[wave] = s1; }
    __syncthreads();
    if (tid == 0) {
        const float vi = (r0[0] + r0[1] + r0[2] + r0[3]) * (1.0f / (float)BATCH);
        const float lm = (r1[0] + r1[1] + r1[2] + r1[3]) * (1.0f / (float)BATCH);
        out[0] = lm + 0.5f * vi;   // total_loss
        out[1] = lm;               // loss_logmse
        out[2] = vi;               // loss_violation
    }
}

extern "C" void kernel_launch(void* const* d_in, const int* in_sizes, int n_in,
                              void* d_out, int out_size, void* d_ws, size_t ws_size,
                              hipStream_t stream)
{
    const float* y_pred = (const float*)d_in[0];
    const float* y_true = (const float*)d_in[1];
    const float* P      = (const float*)d_in[2];
    const float* X      = (const float*)d_in[3];

    float* partial = (float*)d_ws;   // NBLK*2 floats = 16 KB
    avl_main<<<NBLK, 256, 0, stream>>>(y_pred, y_true, P, X, partial);
    avl_final<<<1, 256, 0, stream>>>(partial, (float*)d_out);
}